// Round 20
// baseline (1722.769 us; speedup 1.0000x reference)
//
#include <hip/hip_runtime.h>
#include <cstddef>

#define BB 256
#define TT 256
#define UU 512
#define MM 64
#define NT 512
#define NCACHE 12   // register-cached Wt k-pairs per wave

typedef _Float16 h2 __attribute__((ext_vector_type(2)));
typedef unsigned int uint32;

#define NWTP (UU / 2 * UU)   // 131072 packed words (Wt)
#define NWWP (UU / 2 * MM)   // 16384 packed words (Ww, v4-grouped)
#define NWRP (UU / 2 * MM)   // 16384 packed words (Wr cols 0..63, v4-grouped)

__device__ __forceinline__ uint32 pkf(float lo, float hi) {
    h2 v; v[0] = (_Float16)lo; v[1] = (_Float16)hi;
    return __builtin_bit_cast(uint32, v);
}
__device__ __forceinline__ h2 toh2(uint32 u) { return __builtin_bit_cast(h2, u); }
__device__ __forceinline__ float fd2(uint32 wu, uint32 au, float acc) {
    return __builtin_amdgcn_fdot2(toh2(wu), toh2(au), acc, false);
}

// LDS-only barrier: LDS writes visible, global loads stay in flight.
__device__ __forceinline__ void bar() {
    asm volatile("s_waitcnt lgkmcnt(0)" ::: "memory");
    __builtin_amdgcn_s_barrier();
}
// Compiler fence for same-wave LDS produce->consume (HW DS is wave-ordered).
__device__ __forceinline__ void cfence() {
    asm volatile("" ::: "memory");
}

// One-time weight repack into d_ws (same layouts as r14-r19).
__global__ void cvt_kernel(const float* __restrict__ Wt,
                           const float* __restrict__ Wr,
                           const float* __restrict__ Ww,
                           uint32* __restrict__ Wtp,
                           uint32* __restrict__ Wwp,
                           uint32* __restrict__ Wrp) {
    int i = blockIdx.x * blockDim.x + threadIdx.x;
    const int n = NWTP + NWWP + NWRP;
    for (; i < n; i += gridDim.x * blockDim.x) {
        if (i < NWTP) {
            int k2 = i >> 9, r = i & 511;
            int jj = r >> 3, c = r & 7;
            int col = (c < 4) ? (jj * 4 + c) : (256 + jj * 4 + (c - 4));
            Wtp[i] = pkf(Wt[(size_t)(2 * k2) * UU + col],
                         Wt[(size_t)(2 * k2 + 1) * UU + col]);
        } else if (i < NWTP + NWWP) {
            int o = i - NWTP;
            int k2g = o >> 8, jj = (o >> 2) & 63, c = o & 3;
            int k2 = 4 * k2g + c;
            Wwp[o] = pkf(Ww[(size_t)(2 * k2) * MM + jj],
                         Ww[(size_t)(2 * k2 + 1) * MM + jj]);
        } else {
            int o = i - NWTP - NWWP;
            int k2g = o >> 8, jj = (o >> 2) & 63, c = o & 3;
            int k2 = 4 * k2g + c;
            Wrp[o] = pkf(Wr[(size_t)(2 * k2) * 65 + jj],
                         Wr[(size_t)(2 * k2 + 1) * 65 + jj]);
        }
    }
}

// 256 blocks x 512 threads, 1 batch/block, no grid sync.
// = r19 (3 barriers/step; own-wave GEMV input slices) + pre-issued 4-kp
// streamed-Wt stage at the top of P2: the loads' addresses are independent
// of att2, so issuing them before softmax hides their L2 latency under
// ~400 cycles of softmax+attended VALU (the cfence otherwise pins them).
__global__ __launch_bounds__(NT, 1) void dnc_kernel(
    const float* __restrict__ x,      // [B,T,U]
    const float* __restrict__ mem0,   // [B, M*U]
    const float* __restrict__ Wr,     // [U, M+1]  (fp32, col-64 only)
    const float* __restrict__ br,     // [M+1]
    const float* __restrict__ bt,     // [U]
    const float* __restrict__ bw,     // [M]
    const uint32* __restrict__ Wtp,
    const uint32* __restrict__ Wwp,
    const uint32* __restrict__ Wrp,
    float* __restrict__ out)          // [B,T,U]
{
    const int tid = threadIdx.x;   // 0..511
    const int b   = blockIdx.x;
    const int w   = tid >> 6;      // wave 0..7 (k-chunk, 32 k-pairs each)
    const int jj  = tid & 63;      // lane
    const int ut  = tid;           // owned output column

    __shared__ __align__(16) uint32 Wwl[NWWP];      // 64 KB, persistent
    __shared__ __align__(16) uint32 Wrl[NWRP];      // 64 KB, persistent
    __shared__ __align__(16) float  pWt[8][UU];     // 16 KB k-split partials
    __shared__ __align__(16) float  p1[8][68];      // logits partials + [64]=s64w
    __shared__ __align__(16) float  p2[8][68];
    __shared__ __align__(16) float  lds_rw[8][64];  // per-wave softmax slot
    __shared__ __align__(16) float  lds_ww[8][64];  // per-wave sigmoid slot
    __shared__ __align__(16) uint32 mean2[UU / 2];  // wave-private regions
    __shared__ __align__(16) uint32 att2[UU / 2];
    __shared__ __align__(16) uint32 tr2[UU / 2];

    const uint4* Wp4 = (const uint4*)Wtp;   // [k2][128] uint4 pairs

    // ---- one-time staging: Wwp/Wrp -> LDS (linear uint4 copy) ----
    {
        const uint4* s1 = (const uint4*)Wwp;
        const uint4* s2 = (const uint4*)Wrp;
        uint4* d1 = (uint4*)Wwl;
        uint4* d2 = (uint4*)Wrl;
#pragma unroll
        for (int i = 0; i < 8; ++i) {
            d1[tid + i * 512] = s1[tid + i * 512];
            d2[tid + i * 512] = s2[tid + i * 512];
        }
    }

    // ---- permanent register cache: Wt k-pairs [w*32, w*32+NCACHE) ----
    uint4 wtcL[NCACHE], wtcH[NCACHE];
#pragma unroll
    for (int i = 0; i < NCACHE; ++i) {
        size_t base = (size_t)(w * 32 + i) * 128 + jj * 2;
        wtcL[i] = Wp4[base];
        wtcH[i] = Wp4[base + 1];
    }

    float memc[MM];
#pragma unroll
    for (int m = 0; m < MM; ++m)
        memc[m] = mem0[(size_t)b * (MM * UU) + (size_t)m * UU + ut];

    const float btv  = bt[ut];
    const float wr64 = Wr[(size_t)ut * 65 + 64];
    const float bw_j = bw[jj];
    const float br_j = br[jj];
    const float br64 = br[64];

    float tr_prev = 0.f;
    float xv = x[(size_t)b * TT * UU + ut];

    const uint4* Wwl4 = (const uint4*)Wwl;   // [64 k2g][64 jj]
    const uint4* Wrl4 = (const uint4*)Wrl;
    const uint4* t4   = (const uint4*)tr2;   // [64 k2g]
    const uint4* m4   = (const uint4*)mean2;
    const uint4* a4   = (const uint4*)att2;

    // streamed-Wt base for this lane (constant across t)
    const uint4* sp = Wp4 + (size_t)(w * 32 + NCACHE) * 128 + jj * 2;

    __syncthreads();   // staging visible (outside hot loop, full drain OK)

    for (int t = 0; t < TT; ++t) {
        // ================= P1: sigmoid + mem update + mean + Wr GEMV =======
        if (t > 0) {
            {
                float s = bw_j;
#pragma unroll
                for (int q = 0; q < 8; ++q) s += p2[q][jj];
                lds_ww[w][jj] = 1.f / (1.f + __expf(-s));
            }
            cfence();   // same-wave LDS produce->consume
#pragma unroll
            for (int q = 0; q < 16; ++q) {
                float4 wv = *(const float4*)&lds_ww[w][q * 4];   // own-wave bcast
                memc[q*4+0] = (1.f - wv.x) * memc[q*4+0] + wv.x * tr_prev;
                memc[q*4+1] = (1.f - wv.y) * memc[q*4+1] + wv.y * tr_prev;
                memc[q*4+2] = (1.f - wv.z) * memc[q*4+2] + wv.z * tr_prev;
                memc[q*4+3] = (1.f - wv.w) * memc[q*4+3] + wv.w * tr_prev;
            }
        }
        // mean over M+1 rows (split chains), pack to h2 (own-wave region)
        {
            float c0 = 0.f, c1 = 0.f, c2 = 0.f, c3 = 0.f;
#pragma unroll
            for (int m = 0; m < MM; m += 4) {
                c0 += memc[m]; c1 += memc[m + 1];
                c2 += memc[m + 2]; c3 += memc[m + 3];
            }
            float meanv = ((c0 + c1) + (c2 + c3) + xv) * (1.f / 65.f);
            float mn = __shfl_down(meanv, 1, 64);
            if ((ut & 1) == 0) mean2[ut >> 1] = pkf(meanv, mn);
            float pv = meanv * wr64;
#pragma unroll
            for (int o = 32; o >= 1; o >>= 1) pv += __shfl_xor(pv, o, 64);
            if (jj == 0) p1[w][64] = pv;
        }
        cfence();   // mean2 (own-wave) -> Wr GEMV read
        {
            float pa = 0.f, pb = 0.f;
#pragma unroll
            for (int g = 0; g < 8; ++g) {
                uint4 W = Wrl4[(w * 8 + g) * 64 + jj];
                uint4 M = m4[w * 8 + g];                      // own-wave bcast
                pa = fd2(W.x, M.x, pa);
                pb = fd2(W.y, M.y, pb);
                pa = fd2(W.z, M.z, pa);
                pb = fd2(W.w, M.w, pb);
            }
            p1[w][jj] = pa + pb;
        }
        bar();   // #1: p1 complete across waves

        // ================= P2: stage + softmax + attended + Wt GEMV ========
        // pre-issue 4 streamed k-pairs: addresses independent of att2; their
        // L2 latency hides under the softmax+attended VALU below.
        uint4 sL0 = sp[0],       sH0 = sp[1];
        uint4 sL1 = sp[1 * 128], sH1 = sp[1 * 128 + 1];
        uint4 sL2 = sp[2 * 128], sH2 = sp[2 * 128 + 1];
        uint4 sL3 = sp[3 * 128], sH3 = sp[3 * 128 + 1];

        float rw64;
        {
            float lj = br_j;
#pragma unroll
            for (int q = 0; q < 8; ++q) lj += p1[q][jj];
            float s64 = br64;
#pragma unroll
            for (int q = 0; q < 8; ++q) s64 += p1[q][64];     // broadcast reads
            float l64 = s64;
            float mx = fmaxf(lj, l64);
#pragma unroll
            for (int o = 32; o >= 1; o >>= 1) mx = fmaxf(mx, __shfl_xor(mx, o, 64));
            float e = __expf(lj - mx);
            float e64 = __expf(l64 - mx);
            float sm = e;
#pragma unroll
            for (int o = 32; o >= 1; o >>= 1) sm += __shfl_xor(sm, o, 64);
            sm += e64;
            lds_rw[w][jj] = e / sm;
            rw64 = e64 / sm;
        }
        cfence();   // lds_rw (own-wave) -> attended
        {
            float aa0 = rw64 * xv, aa1 = 0.f;
#pragma unroll
            for (int q = 0; q < 16; q += 2) {
                float4 r0 = *(const float4*)&lds_rw[w][q * 4];
                aa0 += r0.x * memc[q*4+0] + r0.y * memc[q*4+1]
                     + r0.z * memc[q*4+2] + r0.w * memc[q*4+3];
                float4 r1 = *(const float4*)&lds_rw[w][q * 4 + 4];
                aa1 += r1.x * memc[q*4+4] + r1.y * memc[q*4+5]
                     + r1.z * memc[q*4+6] + r1.w * memc[q*4+7];
            }
            float att = aa0 + aa1;
            float an = __shfl_down(att, 1, 64);
            if ((ut & 1) == 0) att2[ut >> 1] = pkf(att, an);
        }
        cfence();   // att2 (own-wave) -> Wt GEMV read
        {
            float acc[8];
#pragma unroll
            for (int c = 0; c < 8; ++c) acc[c] = 0.f;

            auto dot8 = [&](const uint4& L, const uint4& H, uint32 au) {
                acc[0] = fd2(L.x, au, acc[0]);
                acc[1] = fd2(L.y, au, acc[1]);
                acc[2] = fd2(L.z, au, acc[2]);
                acc[3] = fd2(L.w, au, acc[3]);
                acc[4] = fd2(H.x, au, acc[4]);
                acc[5] = fd2(H.y, au, acc[5]);
                acc[6] = fd2(H.z, au, acc[6]);
                acc[7] = fd2(H.w, au, acc[7]);
            };

            // staged 4 k-pairs first (loads issued before softmax)
            dot8(sL0, sH0, att2[w * 32 + NCACHE + 0]);
            dot8(sL1, sH1, att2[w * 32 + NCACHE + 1]);
            dot8(sL2, sH2, att2[w * 32 + NCACHE + 2]);
            dot8(sL3, sH3, att2[w * 32 + NCACHE + 3]);

            // remaining streamed: kp [w*32+NCACHE+4, w*32+32), ONE L/H live
            const uint4* sp2 = sp + (size_t)4 * 128;
#pragma unroll 4
            for (int i = 0; i < 32 - NCACHE - 4; ++i) {
                uint4 L = sp2[(size_t)i * 128];
                uint4 H = sp2[(size_t)i * 128 + 1];
                dot8(L, H, att2[w * 32 + NCACHE + 4 + i]);
            }
            // cached: kp [w*32, w*32+NCACHE), uint4 bcast per quad
#pragma unroll
            for (int g = 0; g < NCACHE / 4; ++g) {
                uint4 A = a4[w * 8 + g];                      // own-wave bcast
                dot8(wtcL[4*g+0], wtcH[4*g+0], A.x);
                dot8(wtcL[4*g+1], wtcH[4*g+1], A.y);
                dot8(wtcL[4*g+2], wtcH[4*g+2], A.z);
                dot8(wtcL[4*g+3], wtcH[4*g+3], A.w);
            }

            *(float4*)&pWt[w][jj * 4]       = make_float4(acc[0], acc[1], acc[2], acc[3]);
            *(float4*)&pWt[w][256 + jj * 4] = make_float4(acc[4], acc[5], acc[6], acc[7]);
        }
        bar();   // #2: pWt complete across waves

        // ================= P3: reduce + store + Ww GEMV (next step) ========
        {
            float s0 = 0.f, s1 = 0.f;
#pragma unroll
            for (int q = 0; q < 8; q += 2) {
                s0 += pWt[q][ut];
                s1 += pWt[q + 1][ut];
            }
            float tr = fmaxf(s0 + s1 + btv, 0.f);
            tr_prev = tr;
            out[(size_t)b * TT * UU + (size_t)t * UU + ut] = tr;
            float trn = __shfl_down(tr, 1, 64);
            if ((ut & 1) == 0) tr2[ut >> 1] = pkf(tr, trn);
        }
        // prefetch next x (register only)
        {
            int tn = (t + 1 < TT) ? t + 1 : t;
            xv = x[(size_t)b * TT * UU + (size_t)tn * UU + ut];
        }
        cfence();   // tr2 (own-wave) -> Ww GEMV read
        if (t + 1 < TT) {
            float pa = 0.f, pb = 0.f;
#pragma unroll
            for (int g = 0; g < 8; ++g) {
                uint4 W = Wwl4[(w * 8 + g) * 64 + jj];       // 4 k-pairs
                uint4 T = t4[w * 8 + g];                      // own-wave bcast
                pa = fd2(W.x, T.x, pa);
                pb = fd2(W.y, T.y, pb);
                pa = fd2(W.z, T.z, pa);
                pb = fd2(W.w, T.w, pb);
            }
            p2[w][jj] = pa + pb;
        }
        bar();   // #3: p2 complete across waves (consumed by P1 of t+1)
    }
}

extern "C" void kernel_launch(void* const* d_in, const int* in_sizes, int n_in,
                              void* d_out, int out_size, void* d_ws, size_t ws_size,
                              hipStream_t stream) {
    const float* x    = (const float*)d_in[0];
    const float* mem0 = (const float*)d_in[1];
    const float* Wr   = (const float*)d_in[2];
    const float* br   = (const float*)d_in[3];
    const float* Wt   = (const float*)d_in[4];
    const float* bt   = (const float*)d_in[5];
    const float* Ww   = (const float*)d_in[6];
    const float* bw   = (const float*)d_in[7];
    float* out = (float*)d_out;

    uint32* Wtp = (uint32*)d_ws;          // [NWTP]
    uint32* Wwp = Wtp + NWTP;             // [NWWP]
    uint32* Wrp = Wwp + NWWP;             // [NWRP]

    cvt_kernel<<<dim3(256), dim3(256), 0, stream>>>(Wt, Wr, Ww, Wtp, Wwp, Wrp);
    dnc_kernel<<<dim3(BB), dim3(NT), 0, stream>>>(
        x, mem0, Wr, br, bt, bw, Wtp, Wwp, Wrp, out);
}

// Round 21
// 1509.628 us; speedup vs baseline: 1.1412x; 1.1412x over previous
//
#include <hip/hip_runtime.h>
#include <cstddef>

#define BB 256
#define TT 256
#define UU 512
#define MM 64
#define NT 512
#define NCACHE 12   // register-cached Wt k-pairs per wave (r16/r19-proven best)

typedef _Float16 h2 __attribute__((ext_vector_type(2)));
typedef unsigned int uint32;

#define NWTP (UU / 2 * UU)   // 131072 packed words (Wt)
#define NWWP (UU / 2 * MM)   // 16384 packed words (Ww, v4-grouped)
#define NWRP (UU / 2 * MM)   // 16384 packed words (Wr cols 0..63, v4-grouped)

__device__ __forceinline__ uint32 pkf(float lo, float hi) {
    h2 v; v[0] = (_Float16)lo; v[1] = (_Float16)hi;
    return __builtin_bit_cast(uint32, v);
}
__device__ __forceinline__ h2 toh2(uint32 u) { return __builtin_bit_cast(h2, u); }
__device__ __forceinline__ float fd2(uint32 wu, uint32 au, float acc) {
    return __builtin_amdgcn_fdot2(toh2(wu), toh2(au), acc, false);
}

// LDS-only barrier: LDS writes visible, global loads stay in flight.
__device__ __forceinline__ void bar() {
    asm volatile("s_waitcnt lgkmcnt(0)" ::: "memory");
    __builtin_amdgcn_s_barrier();
}
// Compiler fence for same-wave LDS produce->consume (HW DS is wave-ordered).
__device__ __forceinline__ void cfence() {
    asm volatile("" ::: "memory");
}

// One-time weight repack into d_ws.
__global__ void cvt_kernel(const float* __restrict__ Wt,
                           const float* __restrict__ Wr,
                           const float* __restrict__ Ww,
                           uint32* __restrict__ Wtp,
                           uint32* __restrict__ Wwp,
                           uint32* __restrict__ Wrp) {
    int i = blockIdx.x * blockDim.x + threadIdx.x;
    const int n = NWTP + NWWP + NWRP;
    for (; i < n; i += gridDim.x * blockDim.x) {
        if (i < NWTP) {
            int k2 = i >> 9, r = i & 511;
            int jj = r >> 3, c = r & 7;
            int col = (c < 4) ? (jj * 4 + c) : (256 + jj * 4 + (c - 4));
            Wtp[i] = pkf(Wt[(size_t)(2 * k2) * UU + col],
                         Wt[(size_t)(2 * k2 + 1) * UU + col]);
        } else if (i < NWTP + NWWP) {
            int o = i - NWTP;
            int k2g = o >> 8, jj = (o >> 2) & 63, c = o & 3;
            int k2 = 4 * k2g + c;
            Wwp[o] = pkf(Ww[(size_t)(2 * k2) * MM + jj],
                         Ww[(size_t)(2 * k2 + 1) * MM + jj]);
        } else {
            int o = i - NWTP - NWWP;
            int k2g = o >> 8, jj = (o >> 2) & 63, c = o & 3;
            int k2 = 4 * k2g + c;
            Wrp[o] = pkf(Wr[(size_t)(2 * k2) * 65 + jj],
                         Wr[(size_t)(2 * k2 + 1) * 65 + jj]);
        }
    }
}

// 256 blocks x 512 threads, 1 batch/block, no grid sync. (= round 19)
// Wave w's GEMV k-chunk reads exactly the vector words its own lanes produce
// (columns [w*64,(w+1)*64)), so producer->GEMV needs only a same-wave cfence.
// Only the three cross-wave partial-sum reductions need barriers: 3/step.
// P1: sigmoid+memupd+mean+WrGEMV | P2: softmax+attended+WtGEMV |
// P3: reduce+store+WwGEMV(next). Wt: 12 kp/wave in regs + 20 streamed;
// Ww/Wr resident in LDS (b128 reads, 0 bank conflicts).
__global__ __launch_bounds__(NT, 1) void dnc_kernel(
    const float* __restrict__ x,      // [B,T,U]
    const float* __restrict__ mem0,   // [B, M*U]
    const float* __restrict__ Wr,     // [U, M+1]  (fp32, col-64 only)
    const float* __restrict__ br,     // [M+1]
    const float* __restrict__ bt,     // [U]
    const float* __restrict__ bw,     // [M]
    const uint32* __restrict__ Wtp,
    const uint32* __restrict__ Wwp,
    const uint32* __restrict__ Wrp,
    float* __restrict__ out)          // [B,T,U]
{
    const int tid = threadIdx.x;   // 0..511
    const int b   = blockIdx.x;
    const int w   = tid >> 6;      // wave 0..7 (k-chunk, 32 k-pairs each)
    const int jj  = tid & 63;      // lane
    const int ut  = tid;           // owned output column

    __shared__ __align__(16) uint32 Wwl[NWWP];      // 64 KB, persistent
    __shared__ __align__(16) uint32 Wrl[NWRP];      // 64 KB, persistent
    __shared__ __align__(16) float  pWt[8][UU];     // 16 KB k-split partials
    __shared__ __align__(16) float  p1[8][68];      // logits partials + [64]=s64w
    __shared__ __align__(16) float  p2[8][68];
    __shared__ __align__(16) float  lds_rw[8][64];  // per-wave softmax slot
    __shared__ __align__(16) float  lds_ww[8][64];  // per-wave sigmoid slot
    __shared__ __align__(16) uint32 mean2[UU / 2];  // wave-private regions
    __shared__ __align__(16) uint32 att2[UU / 2];
    __shared__ __align__(16) uint32 tr2[UU / 2];

    const uint4* Wp4 = (const uint4*)Wtp;   // [k2][128] uint4 pairs

    // ---- one-time staging: Wwp/Wrp -> LDS (linear uint4 copy) ----
    {
        const uint4* s1 = (const uint4*)Wwp;
        const uint4* s2 = (const uint4*)Wrp;
        uint4* d1 = (uint4*)Wwl;
        uint4* d2 = (uint4*)Wrl;
#pragma unroll
        for (int i = 0; i < 8; ++i) {
            d1[tid + i * 512] = s1[tid + i * 512];
            d2[tid + i * 512] = s2[tid + i * 512];
        }
    }

    // ---- permanent register cache: Wt k-pairs [w*32, w*32+NCACHE) ----
    uint4 wtcL[NCACHE], wtcH[NCACHE];
#pragma unroll
    for (int i = 0; i < NCACHE; ++i) {
        size_t base = (size_t)(w * 32 + i) * 128 + jj * 2;
        wtcL[i] = Wp4[base];
        wtcH[i] = Wp4[base + 1];
    }

    float memc[MM];
#pragma unroll
    for (int m = 0; m < MM; ++m)
        memc[m] = mem0[(size_t)b * (MM * UU) + (size_t)m * UU + ut];

    const float btv  = bt[ut];
    const float wr64 = Wr[(size_t)ut * 65 + 64];
    const float bw_j = bw[jj];
    const float br_j = br[jj];
    const float br64 = br[64];

    float tr_prev = 0.f;
    float xv = x[(size_t)b * TT * UU + ut];

    const uint4* Wwl4 = (const uint4*)Wwl;   // [64 k2g][64 jj]
    const uint4* Wrl4 = (const uint4*)Wrl;
    const uint4* t4   = (const uint4*)tr2;   // [64 k2g]
    const uint4* m4   = (const uint4*)mean2;
    const uint4* a4   = (const uint4*)att2;

    __syncthreads();   // staging visible (outside hot loop, full drain OK)

    for (int t = 0; t < TT; ++t) {
        // ================= P1: sigmoid + mem update + mean + Wr GEMV =======
        if (t > 0) {
            // sigmoid over p2 partials (cross-wave, bar'd at end of P3)
            {
                float s = bw_j;
#pragma unroll
                for (int q = 0; q < 8; ++q) s += p2[q][jj];
                lds_ww[w][jj] = 1.f / (1.f + __expf(-s));
            }
            cfence();   // same-wave LDS produce->consume
#pragma unroll
            for (int q = 0; q < 16; ++q) {
                float4 wv = *(const float4*)&lds_ww[w][q * 4];   // own-wave bcast
                memc[q*4+0] = (1.f - wv.x) * memc[q*4+0] + wv.x * tr_prev;
                memc[q*4+1] = (1.f - wv.y) * memc[q*4+1] + wv.y * tr_prev;
                memc[q*4+2] = (1.f - wv.z) * memc[q*4+2] + wv.z * tr_prev;
                memc[q*4+3] = (1.f - wv.w) * memc[q*4+3] + wv.w * tr_prev;
            }
        }
        // mean over M+1 rows (split chains), pack to h2 (own-wave region)
        {
            float c0 = 0.f, c1 = 0.f, c2 = 0.f, c3 = 0.f;
#pragma unroll
            for (int m = 0; m < MM; m += 4) {
                c0 += memc[m]; c1 += memc[m + 1];
                c2 += memc[m + 2]; c3 += memc[m + 3];
            }
            float meanv = ((c0 + c1) + (c2 + c3) + xv) * (1.f / 65.f);
            float mn = __shfl_down(meanv, 1, 64);
            if ((ut & 1) == 0) mean2[ut >> 1] = pkf(meanv, mn);
            float pv = meanv * wr64;
#pragma unroll
            for (int o = 32; o >= 1; o >>= 1) pv += __shfl_xor(pv, o, 64);
            if (jj == 0) p1[w][64] = pv;
        }
        cfence();   // mean2 (own-wave) -> Wr GEMV read
        // Wr GEMV: logits partials (cols 0..63), Wr from LDS, b128
        {
            float pa = 0.f, pb = 0.f;
#pragma unroll
            for (int g = 0; g < 8; ++g) {
                uint4 W = Wrl4[(w * 8 + g) * 64 + jj];
                uint4 M = m4[w * 8 + g];                      // own-wave bcast
                pa = fd2(W.x, M.x, pa);
                pb = fd2(W.y, M.y, pb);
                pa = fd2(W.z, M.z, pa);
                pb = fd2(W.w, M.w, pb);
            }
            p1[w][jj] = pa + pb;
        }
        bar();   // #1: p1 complete across waves

        // ================= P2: softmax + attended + Wt GEMV ================
        float rw64;
        {
            float lj = br_j;
#pragma unroll
            for (int q = 0; q < 8; ++q) lj += p1[q][jj];
            float s64 = br64;
#pragma unroll
            for (int q = 0; q < 8; ++q) s64 += p1[q][64];     // broadcast reads
            float l64 = s64;
            float mx = fmaxf(lj, l64);
#pragma unroll
            for (int o = 32; o >= 1; o >>= 1) mx = fmaxf(mx, __shfl_xor(mx, o, 64));
            float e = __expf(lj - mx);
            float e64 = __expf(l64 - mx);
            float sm = e;
#pragma unroll
            for (int o = 32; o >= 1; o >>= 1) sm += __shfl_xor(sm, o, 64);
            sm += e64;
            lds_rw[w][jj] = e / sm;
            rw64 = e64 / sm;
        }
        cfence();   // lds_rw (own-wave) -> attended
        {
            float aa0 = rw64 * xv, aa1 = 0.f;
#pragma unroll
            for (int q = 0; q < 16; q += 2) {
                float4 r0 = *(const float4*)&lds_rw[w][q * 4];
                aa0 += r0.x * memc[q*4+0] + r0.y * memc[q*4+1]
                     + r0.z * memc[q*4+2] + r0.w * memc[q*4+3];
                float4 r1 = *(const float4*)&lds_rw[w][q * 4 + 4];
                aa1 += r1.x * memc[q*4+4] + r1.y * memc[q*4+5]
                     + r1.z * memc[q*4+6] + r1.w * memc[q*4+7];
            }
            float att = aa0 + aa1;
            float an = __shfl_down(att, 1, 64);
            if ((ut & 1) == 0) att2[ut >> 1] = pkf(att, an);
        }
        cfence();   // att2 (own-wave) -> Wt GEMV read
        {
            float acc[8];
#pragma unroll
            for (int c = 0; c < 8; ++c) acc[c] = 0.f;

            auto dot8 = [&](const uint4& L, const uint4& H, uint32 au) {
                acc[0] = fd2(L.x, au, acc[0]);
                acc[1] = fd2(L.y, au, acc[1]);
                acc[2] = fd2(L.z, au, acc[2]);
                acc[3] = fd2(L.w, au, acc[3]);
                acc[4] = fd2(H.x, au, acc[4]);
                acc[5] = fd2(H.y, au, acc[5]);
                acc[6] = fd2(H.z, au, acc[6]);
                acc[7] = fd2(H.w, au, acc[7]);
            };

            // streamed half: kp [w*32+NCACHE, w*32+32), sequential L/H
            const uint4* sp = Wp4 + (size_t)(w * 32 + NCACHE) * 128 + jj * 2;
#pragma unroll 4
            for (int i = 0; i < 32 - NCACHE; ++i) {
                uint4 L = sp[(size_t)i * 128];
                uint4 H = sp[(size_t)i * 128 + 1];
                dot8(L, H, att2[w * 32 + NCACHE + i]);        // own-wave bcast
            }
            // cached half: kp [w*32, w*32+NCACHE), uint4 bcast per quad
#pragma unroll
            for (int g = 0; g < NCACHE / 4; ++g) {
                uint4 A = a4[w * 8 + g];                      // own-wave bcast
                dot8(wtcL[4*g+0], wtcH[4*g+0], A.x);
                dot8(wtcL[4*g+1], wtcH[4*g+1], A.y);
                dot8(wtcL[4*g+2], wtcH[4*g+2], A.z);
                dot8(wtcL[4*g+3], wtcH[4*g+3], A.w);
            }

            *(float4*)&pWt[w][jj * 4]       = make_float4(acc[0], acc[1], acc[2], acc[3]);
            *(float4*)&pWt[w][256 + jj * 4] = make_float4(acc[4], acc[5], acc[6], acc[7]);
        }
        bar();   // #2: pWt complete across waves

        // ================= P3: reduce + store + Ww GEMV (next step) ========
        {
            float s0 = 0.f, s1 = 0.f;
#pragma unroll
            for (int q = 0; q < 8; q += 2) {
                s0 += pWt[q][ut];
                s1 += pWt[q + 1][ut];
            }
            float tr = fmaxf(s0 + s1 + btv, 0.f);
            tr_prev = tr;
            out[(size_t)b * TT * UU + (size_t)t * UU + ut] = tr;
            float trn = __shfl_down(tr, 1, 64);
            if ((ut & 1) == 0) tr2[ut >> 1] = pkf(tr, trn);
        }
        // prefetch next x (register only)
        {
            int tn = (t + 1 < TT) ? t + 1 : t;
            xv = x[(size_t)b * TT * UU + (size_t)tn * UU + ut];
        }
        cfence();   // tr2 (own-wave) -> Ww GEMV read
        if (t + 1 < TT) {
            float pa = 0.f, pb = 0.f;
#pragma unroll
            for (int g = 0; g < 8; ++g) {
                uint4 W = Wwl4[(w * 8 + g) * 64 + jj];       // 4 k-pairs
                uint4 T = t4[w * 8 + g];                      // own-wave bcast
                pa = fd2(W.x, T.x, pa);
                pb = fd2(W.y, T.y, pb);
                pa = fd2(W.z, T.z, pa);
                pb = fd2(W.w, T.w, pb);
            }
            p2[w][jj] = pa + pb;
        }
        bar();   // #3: p2 complete across waves (consumed by P1 of t+1)
    }
}

extern "C" void kernel_launch(void* const* d_in, const int* in_sizes, int n_in,
                              void* d_out, int out_size, void* d_ws, size_t ws_size,
                              hipStream_t stream) {
    const float* x    = (const float*)d_in[0];
    const float* mem0 = (const float*)d_in[1];
    const float* Wr   = (const float*)d_in[2];
    const float* br   = (const float*)d_in[3];
    const float* Wt   = (const float*)d_in[4];
    const float* bt   = (const float*)d_in[5];
    const float* Ww   = (const float*)d_in[6];
    const float* bw   = (const float*)d_in[7];
    float* out = (float*)d_out;

    uint32* Wtp = (uint32*)d_ws;          // [NWTP]
    uint32* Wwp = Wtp + NWTP;             // [NWWP]
    uint32* Wrp = Wwp + NWWP;             // [NWRP]

    cvt_kernel<<<dim3(256), dim3(256), 0, stream>>>(Wt, Wr, Ww, Wtp, Wwp, Wrp);
    dnc_kernel<<<dim3(BB), dim3(NT), 0, stream>>>(
        x, mem0, Wr, br, bt, bw, Wtp, Wwp, Wrp, out);
}